// Round 5
// baseline (301.722 us; speedup 1.0000x reference)
//
#include <hip/hip_runtime.h>
#include <cstdint>
#include <cstddef>

typedef unsigned short u16;
typedef __attribute__((ext_vector_type(4))) float  float4v;
typedef __attribute__((ext_vector_type(4))) int    int4v;
typedef __attribute__((ext_vector_type(8))) short  short8v;
typedef __attribute__((ext_vector_type(4))) short  short4v;

#define L_SEQ 4096
#define NH 16
#define NKV 4
#define WND 1024

static __device__ __forceinline__ u16 f2bf(float f) {
  union { float f; unsigned u; } v; v.f = f;
  unsigned r = (v.u + 0x7FFFu + ((v.u >> 16) & 1u)) >> 16;  // RNE
  return (u16)r;
}
static __device__ __forceinline__ u16 f2bf_fast(float f) {   // round-half-up, 2 ops
  union { float f; unsigned u; } v; v.f = f;
  return (u16)((v.u + 0x8000u) >> 16);
}
static __device__ __forceinline__ float bf2f(u16 b) {
  union { unsigned u; float f; } v; v.u = ((unsigned)b) << 16;
  return v.f;
}

// ---------------- fp32 -> bf16 elementwise (x4 vectorized) ----------------
__global__ __launch_bounds__(256) void k_cvt(const float* __restrict__ in,
                                             u16* __restrict__ out, int n4) {
  int i = blockIdx.x * 256 + threadIdx.x;
  if (i >= n4) return;
  float4v v = ((const float4v*)in)[i];
  short4v o;
  o[0] = (short)f2bf(v[0]); o[1] = (short)f2bf(v[1]);
  o[2] = (short)f2bf(v[2]); o[3] = (short)f2bf(v[3]);
  ((short4v*)out)[i] = o;
}

// --- transpose+convert 64x64: in fp32 [K][N] -> out bf16 [(row_off+n)][K] ---
__global__ __launch_bounds__(256) void k_transpose64(const float* __restrict__ in,
                                                     u16* __restrict__ out,
                                                     int K, int N, int row_off) {
  __shared__ float tile[64][65];
  int n0 = blockIdx.x * 64, k0 = blockIdx.y * 64;
  int tx = threadIdx.x & 63, ty = threadIdx.x >> 6;
#pragma unroll
  for (int i = 0; i < 16; i++)
    tile[ty + i*4][tx] = in[(size_t)(k0 + ty + i*4)*N + n0 + tx];
  __syncthreads();
#pragma unroll
  for (int i = 0; i < 16; i++)
    out[(size_t)(row_off + n0 + ty + i*4)*K + k0 + tx] = f2bf(tile[tx][ty + i*4]);
}

// --- V extract+transpose: qkvb bf16 [L][3072] cols 2560.. -> vT bf16 [512][L] ---
__global__ __launch_bounds__(256) void k_vtrans(const u16* __restrict__ qkvb,
                                                u16* __restrict__ vT) {
  __shared__ u16 tile[64][66];
  int p0 = blockIdx.x * 64, d0 = blockIdx.y * 64;
  int tx = threadIdx.x & 63, ty = threadIdx.x >> 6;
#pragma unroll
  for (int i = 0; i < 16; i++)
    tile[ty + i*4][tx] = qkvb[(size_t)(p0 + ty + i*4)*3072 + 2560 + d0 + tx];
  __syncthreads();
#pragma unroll
  for (int i = 0; i < 16; i++)
    vT[(size_t)(d0 + ty + i*4)*L_SEQ + p0 + tx] = tile[tx][ty + i*4];
}

// ---------------- bf16 MFMA GEMM, B^T, BK=64, XOR-swizzled LDS ----------------
template<int BF16_OUT>
__global__ __launch_bounds__(256) void k_gemm_bt(const u16* __restrict__ A,
                                                 const u16* __restrict__ B,
                                                 void* __restrict__ Cv,
                                                 int M, int N, int K) {
  __shared__ alignas(16) u16 As[128*64];
  __shared__ alignas(16) u16 Bs[128*64];
  int tid = threadIdx.x;
  int lane = tid & 63, wave = tid >> 6;
  int lr = lane & 15, lg = lane >> 4;
  int m0 = blockIdx.y * 128, n0 = blockIdx.x * 128;
  int wm = (wave >> 1) * 64, wn = (wave & 1) * 64;

  float4v acc[4][4];
#pragma unroll
  for (int i = 0; i < 4; i++)
#pragma unroll
    for (int j = 0; j < 4; j++)
#pragma unroll
      for (int r = 0; r < 4; r++) acc[i][j][r] = 0.f;

  for (int kt = 0; kt < K; kt += 64) {
    __syncthreads();
#pragma unroll
    for (int it = 0; it < 4; it++) {
      int s = it*256 + tid;
      int row = s >> 3, j = s & 7;
      int col = ((j ^ (row & 7)) << 3);
      __builtin_amdgcn_global_load_lds(
          (const __attribute__((address_space(1))) void*)(A + (size_t)(m0 + row)*K + kt + col),
          (__attribute__((address_space(3))) void*)(&As[s * 8]), 16, 0, 0);
      __builtin_amdgcn_global_load_lds(
          (const __attribute__((address_space(1))) void*)(B + (size_t)(n0 + row)*K + kt + col),
          (__attribute__((address_space(3))) void*)(&Bs[s * 8]), 16, 0, 0);
    }
    __syncthreads();
#pragma unroll
    for (int half = 0; half < 2; half++) {
      short8v af[4], bf[4];
#pragma unroll
      for (int i = 0; i < 4; i++) {
        int row = wm + i*16 + lr;
        af[i] = *(const short8v*)(&As[row*64 + ((((half<<2)|lg) ^ (row & 7)) << 3)]);
      }
#pragma unroll
      for (int j = 0; j < 4; j++) {
        int row = wn + j*16 + lr;
        bf[j] = *(const short8v*)(&Bs[row*64 + ((((half<<2)|lg) ^ (row & 7)) << 3)]);
      }
#pragma unroll
      for (int i = 0; i < 4; i++)
#pragma unroll
        for (int j = 0; j < 4; j++)
          acc[i][j] = __builtin_amdgcn_mfma_f32_16x16x32_bf16(af[i], bf[j], acc[i][j], 0, 0, 0);
    }
  }
#pragma unroll
  for (int i = 0; i < 4; i++)
#pragma unroll
    for (int j = 0; j < 4; j++)
#pragma unroll
      for (int r = 0; r < 4; r++) {
        size_t idx = (size_t)(m0 + wm + i*16 + lg*4 + r)*N + (n0 + wn + j*16 + lr);
        if (BF16_OUT) ((u16*)Cv)[idx] = f2bf(acc[i][j][r]);
        else          ((float*)Cv)[idx] = acc[i][j][r];
      }
}

// ---------------- RMSNorm + RoPE for Q,K ----------------
__global__ __launch_bounds__(256) void k_qknorm(const u16* __restrict__ qkvb,
    const int* __restrict__ positions, const float* __restrict__ q_scale,
    const float* __restrict__ k_scale, u16* __restrict__ qb,
    u16* __restrict__ kb) {
  int p = blockIdx.x * 4 + (threadIdx.x >> 6);
  int l = threadIdx.x & 63;
  const float LOG2_BASE = 13.287712379549449f;
  float ang = (float)positions[p] * exp2f(-(float)l * (LOG2_BASE / 64.0f));
  float sn, cs; sincosf(ang, &sn, &cs);
  float qs1 = q_scale[l], qs2 = q_scale[l + 64];
  float ks1 = k_scale[l], ks2 = k_scale[l + 64];
  const u16* base = qkvb + (size_t)p * 3072;
  const float qsc = 0.12751741505539613f;  // 128^-0.5 * log2(e)
#pragma unroll
  for (int h = 0; h < 16; h++) {
    float x1 = bf2f(base[h*128 + l]), x2 = bf2f(base[h*128 + l + 64]);
    float ss = x1*x1 + x2*x2;
#pragma unroll
    for (int m = 1; m < 64; m <<= 1) ss += __shfl_xor(ss, m);
    float rinv = rsqrtf(ss * (1.0f/128.0f) + 1e-6f);
    x1 *= rinv * qs1; x2 *= rinv * qs2;
    u16* dst = qb + ((size_t)p*NH + h)*128;
    dst[l]      = f2bf((x1*cs - x2*sn) * qsc);
    dst[l + 64] = f2bf((x2*cs + x1*sn) * qsc);
  }
#pragma unroll
  for (int g = 0; g < 4; g++) {
    float x1 = bf2f(base[2048 + g*128 + l]), x2 = bf2f(base[2048 + g*128 + l + 64]);
    float ss = x1*x1 + x2*x2;
#pragma unroll
    for (int m = 1; m < 64; m <<= 1) ss += __shfl_xor(ss, m);
    float rinv = rsqrtf(ss * (1.0f/128.0f) + 1e-6f);
    x1 *= rinv * ks1; x2 *= rinv * ks2;
    u16* dst = kb + ((size_t)p*NKV + g)*128;
    dst[l]      = f2bf(x1*cs - x2*sn);
    dst[l + 64] = f2bf(x2*cs + x1*sn);
  }
}

// ---------------- flash attention v4: double-buffered K/V prefetch ----------------
// 32-key tiles, 2 LDS buffers: prefetch tile t+1 issued right after the barrier,
// compute on tile t -> global-load latency hidden behind a full compute phase.
// XCD decode with chunk interleave: each XCD gets q-chunks {2c+(xcd&1)} -> balanced
// work AND per-XCD K/V footprint ~3.1 MB (4 disjoint windows) < 4 MB L2.
// Fixed-max softmax (RMSNorm bounds |S|), denom via MFMA-with-ones.
__global__ __launch_bounds__(256) void k_attn(const u16* __restrict__ qb,
    const u16* __restrict__ kb, const u16* __restrict__ vT,
    u16* __restrict__ ob) {
  __shared__ alignas(16) u16 Ks[2][32*128];   // [key][dim], chunk j at slot j^(row&15)
  __shared__ alignas(16) u16 Vs[2][128*32];   // [dim][key], chunk j at slot j^(row&3)
  __shared__ alignas(16) u16 Pw[4][2][16*40]; // per-wave P transpose, pad 32->40
  int tid = threadIdx.x;
  int lane = tid & 63, wave = tid >> 6;
  int lr = lane & 15, lg = lane >> 4;
  int flat = blockIdx.x;
  int xcd = flat & 7, s = flat >> 3;
  int gh = xcd >> 1;
  int chunk = s >> 4;                               // 0..3: 512-query chunks
  int qtile = (chunk*2 + (xcd & 1))*16 + (s & 15);  // interleaved chunk ownership
  int q0 = qtile * 32;
  int h = gh * 4 + wave;

  short8v qf[2][4];
#pragma unroll
  for (int m = 0; m < 2; m++) {
    const u16* qrow = qb + ((size_t)(q0 + m*16 + lr)*NH + h)*128 + lg*8;
#pragma unroll
    for (int t = 0; t < 4; t++) qf[m][t] = *(const short8v*)(qrow + t*32);
  }

  const short one_bf = (short)0x3F80;
  const short8v ones = {one_bf,one_bf,one_bf,one_bf,one_bf,one_bf,one_bf,one_bf};

  float4v O[8][2], den[2];
#pragma unroll
  for (int dt = 0; dt < 8; dt++)
#pragma unroll
    for (int m = 0; m < 2; m++)
#pragma unroll
      for (int r = 0; r < 4; r++) O[dt][m][r] = 0.f;
#pragma unroll
  for (int m = 0; m < 2; m++)
#pragma unroll
    for (int r = 0; r < 4; r++) den[m][r] = 0.f;

  auto stage = [&](int buf, int kt) {
#pragma unroll
    for (int it = 0; it < 2; it++) {
      int s2 = it*256 + tid;
      { int row = s2 >> 4, j = s2 & 15, col = (j ^ (row & 15)) << 3;
        __builtin_amdgcn_global_load_lds(
            (const __attribute__((address_space(1))) void*)(kb + (size_t)(kt + row)*512 + gh*128 + col),
            (__attribute__((address_space(3))) void*)(&Ks[buf][s2 * 8]), 16, 0, 0); }
      { int row = s2 >> 2, j = s2 & 3, col = (j ^ (row & 3)) << 3;
        __builtin_amdgcn_global_load_lds(
            (const __attribute__((address_space(1))) void*)(vT + (size_t)(gh*128 + row)*L_SEQ + kt + col),
            (__attribute__((address_space(3))) void*)(&Vs[buf][s2 * 8]), 16, 0, 0); }
    }
  };

  int kstart = q0 - (WND - 1); if (kstart < 0) kstart = 0; kstart &= ~31;
  stage(0, kstart);
  int cur = 0;
  for (int kt = kstart; kt < q0 + 32; kt += 32) {
    __syncthreads();                 // drains vmcnt: buf[cur] ready, prev readers done
    if (kt + 32 < q0 + 32) stage(cur ^ 1, kt + 32);   // prefetch overlaps compute below

    float4v S[2][2];
#pragma unroll
    for (int m = 0; m < 2; m++)
#pragma unroll
      for (int t2 = 0; t2 < 2; t2++)
#pragma unroll
        for (int r = 0; r < 4; r++) S[m][t2][r] = 0.f;
#pragma unroll
    for (int t2 = 0; t2 < 2; t2++) {
      int row = t2*16 + lr;
#pragma unroll
      for (int t = 0; t < 4; t++) {
        short8v kf = *(const short8v*)(&Ks[cur][row*128 + (((t*4 + lg) ^ (row & 15)) << 3)]);
        S[0][t2] = __builtin_amdgcn_mfma_f32_16x16x32_bf16(qf[0][t], kf, S[0][t2], 0, 0, 0);
        S[1][t2] = __builtin_amdgcn_mfma_f32_16x16x32_bf16(qf[1][t], kf, S[1][t2], 0, 0, 0);
      }
    }

    bool need_mask = (kt + 32 > q0) || (kt < q0 - (WND - 32));
    if (need_mask) {
#pragma unroll
      for (int m = 0; m < 2; m++)
#pragma unroll
        for (int r = 0; r < 4; r++) {
          int pos = q0 + m*16 + lg*4 + r;
#pragma unroll
          for (int t2 = 0; t2 < 2; t2++) {
            int key = kt + t2*16 + lr;
            float p = (key > pos || key < pos - (WND - 1)) ? 0.f : exp2f(S[m][t2][r]);
            Pw[wave][m][(lg*4 + r)*40 + t2*16 + lr] = f2bf_fast(p);
          }
        }
    } else {
#pragma unroll
      for (int m = 0; m < 2; m++)
#pragma unroll
        for (int r = 0; r < 4; r++)
#pragma unroll
          for (int t2 = 0; t2 < 2; t2++)
            Pw[wave][m][(lg*4 + r)*40 + t2*16 + lr] = f2bf_fast(exp2f(S[m][t2][r]));
    }

    short8v pf[2];
#pragma unroll
    for (int m = 0; m < 2; m++)
      pf[m] = *(const short8v*)(&Pw[wave][m][lr*40 + lg*8]);  // wave-private: no barrier

#pragma unroll
    for (int dt = 0; dt < 8; dt++) {
      int row = dt*16 + lr;
      short8v vf = *(const short8v*)(&Vs[cur][row*32 + ((lg ^ (row & 3)) << 3)]);
      O[dt][0] = __builtin_amdgcn_mfma_f32_16x16x32_bf16(pf[0], vf, O[dt][0], 0, 0, 0);
      O[dt][1] = __builtin_amdgcn_mfma_f32_16x16x32_bf16(pf[1], vf, O[dt][1], 0, 0, 0);
    }
    den[0] = __builtin_amdgcn_mfma_f32_16x16x32_bf16(pf[0], ones, den[0], 0, 0, 0);
    den[1] = __builtin_amdgcn_mfma_f32_16x16x32_bf16(pf[1], ones, den[1], 0, 0, 0);
    cur ^= 1;
  }

#pragma unroll
  for (int m = 0; m < 2; m++)
#pragma unroll
    for (int r = 0; r < 4; r++) {
      float inv = 1.0f / den[m][r];
#pragma unroll
      for (int dt = 0; dt < 8; dt++)
        ob[((size_t)(q0 + m*16 + lg*4 + r)*NH + h)*128 + dt*16 + lr] =
            f2bf(O[dt][m][r] * inv);
    }
}

extern "C" void kernel_launch(void* const* d_in, const int* in_sizes, int n_in,
                              void* d_out, int out_size, void* d_ws, size_t ws_size,
                              hipStream_t stream) {
  (void)in_sizes; (void)n_in; (void)out_size; (void)ws_size;
  const float* x        = (const float*)d_in[0];
  const int*   positions= (const int*)d_in[1];
  const float* Wq       = (const float*)d_in[2];
  const float* Wk       = (const float*)d_in[3];
  const float* Wv       = (const float*)d_in[4];
  const float* Wo       = (const float*)d_in[5];
  const float* q_scale  = (const float*)d_in[6];
  const float* k_scale  = (const float*)d_in[7];
  float* out = (float*)d_out;

  char* ws = (char*)d_ws;
  u16* xb   = (u16*)ws; ws += (size_t)4096*2048*2;
  u16* Wt   = (u16*)ws; ws += (size_t)3072*2048*2;
  u16* Wot  = (u16*)ws; ws += (size_t)2048*2048*2;
  u16* qkvb = (u16*)ws; ws += (size_t)4096*3072*2;
  u16* qb   = (u16*)ws; ws += (size_t)4096*2048*2;
  u16* kb   = (u16*)ws; ws += (size_t)4096*512*2;
  u16* vT   = (u16*)ws; ws += (size_t)4096*512*2;
  u16* ob   = qkvb;

  k_cvt<<<8192, 256, 0, stream>>>(x, xb, 2097152);
  k_transpose64<<<dim3(32,32), 256, 0, stream>>>(Wq, Wt, 2048, 2048, 0);
  k_transpose64<<<dim3(8,32),  256, 0, stream>>>(Wk, Wt, 2048, 512, 2048);
  k_transpose64<<<dim3(8,32),  256, 0, stream>>>(Wv, Wt, 2048, 512, 2560);
  k_transpose64<<<dim3(32,32), 256, 0, stream>>>(Wo, Wot, 2048, 2048, 0);
  k_gemm_bt<1><<<dim3(24,32), 256, 0, stream>>>(xb, Wt, qkvb, 4096, 3072, 2048);
  k_qknorm<<<1024, 256, 0, stream>>>(qkvb, positions, q_scale, k_scale, qb, kb);
  k_vtrans<<<dim3(64,8), 256, 0, stream>>>(qkvb, vT);
  k_attn<<<512, 256, 0, stream>>>(qb, kb, vT, ob);
  k_gemm_bt<0><<<dim3(16,32), 256, 0, stream>>>(ob, Wot, out, 4096, 2048, 2048);
}

// Round 6
// 295.860 us; speedup vs baseline: 1.0198x; 1.0198x over previous
//
#include <hip/hip_runtime.h>
#include <cstdint>
#include <cstddef>

typedef unsigned short u16;
typedef __attribute__((ext_vector_type(4))) float  float4v;
typedef __attribute__((ext_vector_type(4))) int    int4v;
typedef __attribute__((ext_vector_type(8))) short  short8v;
typedef __attribute__((ext_vector_type(4))) short  short4v;

#define L_SEQ 4096
#define NH 16
#define NKV 4
#define WND 1024

static __device__ __forceinline__ u16 f2bf(float f) {
  union { float f; unsigned u; } v; v.f = f;
  unsigned r = (v.u + 0x7FFFu + ((v.u >> 16) & 1u)) >> 16;  // RNE
  return (u16)r;
}
static __device__ __forceinline__ u16 f2bf_fast(float f) {   // round-half-up, 2 ops
  union { float f; unsigned u; } v; v.f = f;
  return (u16)((v.u + 0x8000u) >> 16);
}
static __device__ __forceinline__ float bf2f(u16 b) {
  union { unsigned u; float f; } v; v.u = ((unsigned)b) << 16;
  return v.f;
}

// ---------------- fused prep: x cvt + 4 weight transposes ----------------
// blocks [0,8192): cvt x fp32->bf16 (float4 per thread)
// blocks [8192,...): 64x64 transpose tiles for Wq|Wk|Wv -> Wt, Wo -> Wot
__global__ __launch_bounds__(256) void k_prep(const float* __restrict__ x,
    const float* __restrict__ Wq, const float* __restrict__ Wk,
    const float* __restrict__ Wv, const float* __restrict__ Wo,
    u16* __restrict__ xb, u16* __restrict__ Wt, u16* __restrict__ Wot) {
  int b = blockIdx.x;
  if (b < 8192) {
    int i = b * 256 + threadIdx.x;
    float4v v = ((const float4v*)x)[i];
    short4v o;
    o[0] = (short)f2bf(v[0]); o[1] = (short)f2bf(v[1]);
    o[2] = (short)f2bf(v[2]); o[3] = (short)f2bf(v[3]);
    ((short4v*)xb)[i] = o;
    return;
  }
  __shared__ float tile[64][65];
  b -= 8192;
  const float* in; u16* out; int N, ro, nx;
  if (b < 1024)      {           in = Wq; out = Wt;  N = 2048; ro = 0;    nx = 32; }
  else if (b < 1280) { b -= 1024; in = Wk; out = Wt;  N = 512;  ro = 2048; nx = 8; }
  else if (b < 1536) { b -= 1280; in = Wv; out = Wt;  N = 512;  ro = 2560; nx = 8; }
  else               { b -= 1536; in = Wo; out = Wot; N = 2048; ro = 0;    nx = 32; }
  const int K = 2048;
  int n0 = (b % nx) * 64, k0 = (b / nx) * 64;
  int tx = threadIdx.x & 63, ty = threadIdx.x >> 6;
#pragma unroll
  for (int i = 0; i < 16; i++)
    tile[ty + i*4][tx] = in[(size_t)(k0 + ty + i*4)*N + n0 + tx];
  __syncthreads();
#pragma unroll
  for (int i = 0; i < 16; i++)
    out[(size_t)(ro + n0 + ty + i*4)*K + k0 + tx] = f2bf(tile[tx][ty + i*4]);
}

// ---------------- bf16 MFMA GEMM, B^T, BK=64, XOR-swizzled LDS ----------------
template<int BF16_OUT>
__global__ __launch_bounds__(256) void k_gemm_bt(const u16* __restrict__ A,
                                                 const u16* __restrict__ B,
                                                 void* __restrict__ Cv,
                                                 int M, int N, int K) {
  __shared__ alignas(16) u16 As[128*64];
  __shared__ alignas(16) u16 Bs[128*64];
  int tid = threadIdx.x;
  int lane = tid & 63, wave = tid >> 6;
  int lr = lane & 15, lg = lane >> 4;
  int m0 = blockIdx.y * 128, n0 = blockIdx.x * 128;
  int wm = (wave >> 1) * 64, wn = (wave & 1) * 64;

  float4v acc[4][4];
#pragma unroll
  for (int i = 0; i < 4; i++)
#pragma unroll
    for (int j = 0; j < 4; j++)
#pragma unroll
      for (int r = 0; r < 4; r++) acc[i][j][r] = 0.f;

  for (int kt = 0; kt < K; kt += 64) {
    __syncthreads();
#pragma unroll
    for (int it = 0; it < 4; it++) {
      int s = it*256 + tid;
      int row = s >> 3, j = s & 7;
      int col = ((j ^ (row & 7)) << 3);
      __builtin_amdgcn_global_load_lds(
          (const __attribute__((address_space(1))) void*)(A + (size_t)(m0 + row)*K + kt + col),
          (__attribute__((address_space(3))) void*)(&As[s * 8]), 16, 0, 0);
      __builtin_amdgcn_global_load_lds(
          (const __attribute__((address_space(1))) void*)(B + (size_t)(n0 + row)*K + kt + col),
          (__attribute__((address_space(3))) void*)(&Bs[s * 8]), 16, 0, 0);
    }
    __syncthreads();
#pragma unroll
    for (int half = 0; half < 2; half++) {
      short8v af[4], bf[4];
#pragma unroll
      for (int i = 0; i < 4; i++) {
        int row = wm + i*16 + lr;
        af[i] = *(const short8v*)(&As[row*64 + ((((half<<2)|lg) ^ (row & 7)) << 3)]);
      }
#pragma unroll
      for (int j = 0; j < 4; j++) {
        int row = wn + j*16 + lr;
        bf[j] = *(const short8v*)(&Bs[row*64 + ((((half<<2)|lg) ^ (row & 7)) << 3)]);
      }
#pragma unroll
      for (int i = 0; i < 4; i++)
#pragma unroll
        for (int j = 0; j < 4; j++)
          acc[i][j] = __builtin_amdgcn_mfma_f32_16x16x32_bf16(af[i], bf[j], acc[i][j], 0, 0, 0);
    }
  }
#pragma unroll
  for (int i = 0; i < 4; i++)
#pragma unroll
    for (int j = 0; j < 4; j++)
#pragma unroll
      for (int r = 0; r < 4; r++) {
        size_t idx = (size_t)(m0 + wm + i*16 + lg*4 + r)*N + (n0 + wn + j*16 + lr);
        if (BF16_OUT) ((u16*)Cv)[idx] = f2bf(acc[i][j][r]);
        else          ((float*)Cv)[idx] = acc[i][j][r];
      }
}

// ---------------- fused post: RMSNorm+RoPE (Q,K) + V transpose ----------------
// blocks [0,1024): qknorm (4 positions per block, 1 wave each)
// blocks [1024,1536): V extract+transpose 64x64 tiles -> vT [512][L]
__global__ __launch_bounds__(256) void k_post(const u16* __restrict__ qkvb,
    const int* __restrict__ positions, const float* __restrict__ q_scale,
    const float* __restrict__ k_scale, u16* __restrict__ qb,
    u16* __restrict__ kb, u16* __restrict__ vT) {
  int b = blockIdx.x;
  if (b < 1024) {
    int p = b * 4 + (threadIdx.x >> 6);
    int l = threadIdx.x & 63;
    const float LOG2_BASE = 13.287712379549449f;
    float ang = (float)positions[p] * exp2f(-(float)l * (LOG2_BASE / 64.0f));
    float sn, cs; sincosf(ang, &sn, &cs);
    float qs1 = q_scale[l], qs2 = q_scale[l + 64];
    float ks1 = k_scale[l], ks2 = k_scale[l + 64];
    const u16* base = qkvb + (size_t)p * 3072;
    const float qsc = 0.12751741505539613f;  // 128^-0.5 * log2(e)
#pragma unroll
    for (int h = 0; h < 16; h++) {
      float x1 = bf2f(base[h*128 + l]), x2 = bf2f(base[h*128 + l + 64]);
      float ss = x1*x1 + x2*x2;
#pragma unroll
      for (int m = 1; m < 64; m <<= 1) ss += __shfl_xor(ss, m);
      float rinv = rsqrtf(ss * (1.0f/128.0f) + 1e-6f);
      x1 *= rinv * qs1; x2 *= rinv * qs2;
      u16* dst = qb + ((size_t)p*NH + h)*128;
      dst[l]      = f2bf((x1*cs - x2*sn) * qsc);
      dst[l + 64] = f2bf((x2*cs + x1*sn) * qsc);
    }
#pragma unroll
    for (int g = 0; g < 4; g++) {
      float x1 = bf2f(base[2048 + g*128 + l]), x2 = bf2f(base[2048 + g*128 + l + 64]);
      float ss = x1*x1 + x2*x2;
#pragma unroll
      for (int m = 1; m < 64; m <<= 1) ss += __shfl_xor(ss, m);
      float rinv = rsqrtf(ss * (1.0f/128.0f) + 1e-6f);
      x1 *= rinv * ks1; x2 *= rinv * ks2;
      u16* dst = kb + ((size_t)p*NKV + g)*128;
      dst[l]      = f2bf(x1*cs - x2*sn);
      dst[l + 64] = f2bf(x2*cs + x1*sn);
    }
    return;
  }
  __shared__ u16 tile[64][66];
  int b2 = b - 1024;
  int p0 = (b2 & 63) * 64, d0 = (b2 >> 6) * 64;
  int tx = threadIdx.x & 63, ty = threadIdx.x >> 6;
#pragma unroll
  for (int i = 0; i < 16; i++)
    tile[ty + i*4][tx] = qkvb[(size_t)(p0 + ty + i*4)*3072 + 2560 + d0 + tx];
  __syncthreads();
#pragma unroll
  for (int i = 0; i < 16; i++)
    vT[(size_t)(d0 + ty + i*4)*L_SEQ + p0 + tx] = tile[tx][ty + i*4];
}

// ---------------- flash attention v5: dbuf prefetch + pair-swizzled Vs ----------------
// 32-key tiles, 2 LDS buffers, XCD-interleaved q-chunk ownership.
// Vs staged in 128 B row-PAIRS with chunk slot j^(pair&7): DMA lane-contiguous,
// fragment reads spread to 2-way banks (free) -- fixes R5's 4-way conflicts.
// Fixed-max softmax (RMSNorm bounds |S|), denominator via MFMA-with-ones.
__global__ __launch_bounds__(256) void k_attn(const u16* __restrict__ qb,
    const u16* __restrict__ kb, const u16* __restrict__ vT,
    u16* __restrict__ ob) {
  __shared__ alignas(16) u16 Ks[2][32*128];   // [key][dim], chunk j at slot j^(row&15)
  __shared__ alignas(16) u16 Vs[2][128*32];   // [dim][key] in row-pairs, slot j^(pair&7)
  __shared__ alignas(16) u16 Pw[4][2][16*40]; // per-wave P transpose, pad 32->40
  int tid = threadIdx.x;
  int lane = tid & 63, wave = tid >> 6;
  int lr = lane & 15, lg = lane >> 4;
  int flat = blockIdx.x;
  int xcd = flat & 7, s = flat >> 3;
  int gh = xcd >> 1;
  int chunk = s >> 4;
  int qtile = (chunk*2 + (xcd & 1))*16 + (s & 15);
  int q0 = qtile * 32;
  int h = gh * 4 + wave;

  short8v qf[2][4];
#pragma unroll
  for (int m = 0; m < 2; m++) {
    const u16* qrow = qb + ((size_t)(q0 + m*16 + lr)*NH + h)*128 + lg*8;
#pragma unroll
    for (int t = 0; t < 4; t++) qf[m][t] = *(const short8v*)(qrow + t*32);
  }

  const short one_bf = (short)0x3F80;
  const short8v ones = {one_bf,one_bf,one_bf,one_bf,one_bf,one_bf,one_bf,one_bf};

  float4v O[8][2], den[2];
#pragma unroll
  for (int dt = 0; dt < 8; dt++)
#pragma unroll
    for (int m = 0; m < 2; m++)
#pragma unroll
      for (int r = 0; r < 4; r++) O[dt][m][r] = 0.f;
#pragma unroll
  for (int m = 0; m < 2; m++)
#pragma unroll
    for (int r = 0; r < 4; r++) den[m][r] = 0.f;

  auto stage = [&](int buf, int kt) {
#pragma unroll
    for (int it = 0; it < 2; it++) {
      int s2 = it*256 + tid;
      { int row = s2 >> 4, j = s2 & 15, col = (j ^ (row & 15)) << 3;
        __builtin_amdgcn_global_load_lds(
            (const __attribute__((address_space(1))) void*)(kb + (size_t)(kt + row)*512 + gh*128 + col),
            (__attribute__((address_space(3))) void*)(&Ks[buf][s2 * 8]), 16, 0, 0); }
      { int g = s2 >> 3, sl = s2 & 7, j = sl ^ (g & 7);
        int row = 2*g + (j >> 2), col = (j & 3) << 3;
        __builtin_amdgcn_global_load_lds(
            (const __attribute__((address_space(1))) void*)(vT + (size_t)(gh*128 + row)*L_SEQ + kt + col),
            (__attribute__((address_space(3))) void*)(&Vs[buf][s2 * 8]), 16, 0, 0); }
    }
  };

  int kstart = q0 - (WND - 1); if (kstart < 0) kstart = 0; kstart &= ~31;
  stage(0, kstart);
  int cur = 0;
  for (int kt = kstart; kt < q0 + 32; kt += 32) {
    __syncthreads();                 // buf[cur] ready, prev readers done
    if (kt + 32 < q0 + 32) stage(cur ^ 1, kt + 32);   // prefetch overlaps compute

    float4v S[2][2];
#pragma unroll
    for (int m = 0; m < 2; m++)
#pragma unroll
      for (int t2 = 0; t2 < 2; t2++)
#pragma unroll
        for (int r = 0; r < 4; r++) S[m][t2][r] = 0.f;
#pragma unroll
    for (int t2 = 0; t2 < 2; t2++) {
      int row = t2*16 + lr;
#pragma unroll
      for (int t = 0; t < 4; t++) {
        short8v kf = *(const short8v*)(&Ks[cur][row*128 + (((t*4 + lg) ^ (row & 15)) << 3)]);
        S[0][t2] = __builtin_amdgcn_mfma_f32_16x16x32_bf16(qf[0][t], kf, S[0][t2], 0, 0, 0);
        S[1][t2] = __builtin_amdgcn_mfma_f32_16x16x32_bf16(qf[1][t], kf, S[1][t2], 0, 0, 0);
      }
    }

    bool need_mask = (kt + 32 > q0) || (kt < q0 - (WND - 32));
    if (need_mask) {
#pragma unroll
      for (int m = 0; m < 2; m++)
#pragma unroll
        for (int r = 0; r < 4; r++) {
          int pos = q0 + m*16 + lg*4 + r;
#pragma unroll
          for (int t2 = 0; t2 < 2; t2++) {
            int key = kt + t2*16 + lr;
            float p = (key > pos || key < pos - (WND - 1)) ? 0.f : exp2f(S[m][t2][r]);
            Pw[wave][m][(lg*4 + r)*40 + t2*16 + lr] = f2bf_fast(p);
          }
        }
    } else {
#pragma unroll
      for (int m = 0; m < 2; m++)
#pragma unroll
        for (int r = 0; r < 4; r++)
#pragma unroll
          for (int t2 = 0; t2 < 2; t2++)
            Pw[wave][m][(lg*4 + r)*40 + t2*16 + lr] = f2bf_fast(exp2f(S[m][t2][r]));
    }

    short8v pf[2];
#pragma unroll
    for (int m = 0; m < 2; m++)
      pf[m] = *(const short8v*)(&Pw[wave][m][lr*40 + lg*8]);  // wave-private: no barrier

#pragma unroll
    for (int dt = 0; dt < 8; dt++) {
      int r0 = dt*16 + lr;
      int g = r0 >> 1;
      int sl = ((((r0 & 1) << 2) | lg) ^ (g & 7));
      short8v vf = *(const short8v*)(&Vs[cur][g*64 + sl*8]);
      O[dt][0] = __builtin_amdgcn_mfma_f32_16x16x32_bf16(pf[0], vf, O[dt][0], 0, 0, 0);
      O[dt][1] = __builtin_amdgcn_mfma_f32_16x16x32_bf16(pf[1], vf, O[dt][1], 0, 0, 0);
    }
    den[0] = __builtin_amdgcn_mfma_f32_16x16x32_bf16(pf[0], ones, den[0], 0, 0, 0);
    den[1] = __builtin_amdgcn_mfma_f32_16x16x32_bf16(pf[1], ones, den[1], 0, 0, 0);
    cur ^= 1;
  }

#pragma unroll
  for (int m = 0; m < 2; m++)
#pragma unroll
    for (int r = 0; r < 4; r++) {
      float inv = 1.0f / den[m][r];
#pragma unroll
      for (int dt = 0; dt < 8; dt++)
        ob[((size_t)(q0 + m*16 + lg*4 + r)*NH + h)*128 + dt*16 + lr] =
            f2bf(O[dt][m][r] * inv);
    }
}

extern "C" void kernel_launch(void* const* d_in, const int* in_sizes, int n_in,
                              void* d_out, int out_size, void* d_ws, size_t ws_size,
                              hipStream_t stream) {
  (void)in_sizes; (void)n_in; (void)out_size; (void)ws_size;
  const float* x        = (const float*)d_in[0];
  const int*   positions= (const int*)d_in[1];
  const float* Wq       = (const float*)d_in[2];
  const float* Wk       = (const float*)d_in[3];
  const float* Wv       = (const float*)d_in[4];
  const float* Wo       = (const float*)d_in[5];
  const float* q_scale  = (const float*)d_in[6];
  const float* k_scale  = (const float*)d_in[7];
  float* out = (float*)d_out;

  char* ws = (char*)d_ws;
  u16* xb   = (u16*)ws; ws += (size_t)4096*2048*2;
  u16* Wt   = (u16*)ws; ws += (size_t)3072*2048*2;
  u16* Wot  = (u16*)ws; ws += (size_t)2048*2048*2;
  u16* qkvb = (u16*)ws; ws += (size_t)4096*3072*2;
  u16* qb   = (u16*)ws; ws += (size_t)4096*2048*2;
  u16* kb   = (u16*)ws; ws += (size_t)4096*512*2;
  u16* vT   = (u16*)ws; ws += (size_t)4096*512*2;
  u16* ob   = qkvb;

  k_prep<<<10752, 256, 0, stream>>>(x, Wq, Wk, Wv, Wo, xb, Wt, Wot);
  k_gemm_bt<1><<<dim3(24,32), 256, 0, stream>>>(xb, Wt, qkvb, 4096, 3072, 2048);
  k_post<<<1536, 256, 0, stream>>>(qkvb, positions, q_scale, k_scale, qb, kb, vT);
  k_attn<<<512, 256, 0, stream>>>(qb, kb, vT, ob);
  k_gemm_bt<0><<<dim3(16,32), 256, 0, stream>>>(ob, Wot, out, 4096, 2048, 2048);
}